// Round 9
// baseline (1856.145 us; speedup 1.0000x reference)
//
#include <hip/hip_runtime.h>
#include <hip/hip_bf16.h>
#include <math.h>

// B=4096 queries, D=256, K=65536 centroids (f32).
// Round 9: round-8 filter architecture with correctness hardening:
//   - EXACT float-order packing for the final decision (no +1024 quantization)
//   - margin doubled: 2^-7 sqrt(xsq*cmaxsq) + 1.0
//   - CAP 524288 pairs; brute-force exact fallback if a query has no rescored pair.
// 1-term f16 MFMA scan -> per-(q, 32c-group) min (dense) -> threshold -> exact f32
// rescore of selected groups -> packed-u64 atomicMin -> gather (+fallback).

#define DDIM 256
#define STSZ 4096      // centroids per strip
#define QT 256         // queries per scan block
#define CAP 524288     // pair-list capacity (expected ~5-10k)
#define F16_MINN 6.103515625e-5f

typedef __attribute__((ext_vector_type(8))) _Float16 half8;
typedef __attribute__((ext_vector_type(4))) _Float16 half4;
typedef __attribute__((ext_vector_type(4))) float f32x4;

__device__ __forceinline__ void gl_lds16(const void* g, void* l) {
  __builtin_amdgcn_global_load_lds((const __attribute__((address_space(1))) void*)g,
                                   (__attribute__((address_space(3))) void*)l, 16, 0, 0);
}

// exact order-preserving float -> uint key (finite floats; matches f32 <)
__device__ __forceinline__ unsigned fkey(float d) {
  unsigned ud = __float_as_uint(d);
  return ud ^ (((int)ud < 0) ? 0xFFFFFFFFu : 0x80000000u);
}

// ---------------- ctl init: [0]=pair count, [32]=cmax_sq bits ----------------
__global__ void initctl_kernel(unsigned* __restrict__ ctl) {
  if (threadIdx.x < 64) ctl[threadIdx.x] = 0u;
}

// ---------------- hi split: f32 -> f16 (subnormals clamped to 0) ----------------
__global__ __launch_bounds__(256) void splitx_kernel(const float* __restrict__ in,
                                                     _Float16* __restrict__ o0, int n4) {
  int i = blockIdx.x * 256 + threadIdx.x;
  if (i >= n4) return;
  float4 v = ((const float4*)in)[i];
  float vv[4] = {v.x, v.y, v.z, v.w};
  half4 h0;
#pragma unroll
  for (int e = 0; e < 4; ++e)
    h0[e] = (fabsf(vv[e]) < F16_MINN) ? (_Float16)0.f : (_Float16)vv[e];
  *(half4*)(o0 + (size_t)i * 4) = h0;
}

// ---------------- c_sq (exact f32) + max ||c||^2 ----------------
__global__ __launch_bounds__(256) void csq_kernel(const float* __restrict__ cent,
                                                  float* __restrict__ c_sq,
                                                  unsigned* __restrict__ ctl) {
  int gtid = blockIdx.x * 256 + threadIdx.x;
  int c = gtid >> 6;
  int lane = threadIdx.x & 63;
  float4 v = ((const float4*)(cent + (size_t)c * DDIM))[lane];
  float s = v.x * v.x + v.y * v.y + v.z * v.z + v.w * v.w;
#pragma unroll
  for (int off = 32; off > 0; off >>= 1) s += __shfl_down(s, off, 64);
  if (lane == 0) {
    c_sq[c] = s;
    atomicMax(&ctl[32], __float_as_uint(s));  // positive floats: uint order == float order
  }
}

// ---------------- scan: hi-only MFMA, min per (q, 32c-group) ----------------
// Grid 256 blocks (XCD-swizzled), 512 threads (8 waves). Block: 256 q x 4096 c strip.
// A LDS layout: [kt 8][quad 4][row 256][8 f16]. Wave w owns c-slice w*32 of each
// 256-c subtile (group = (kc,ct,w)).
__global__ __launch_bounds__(512, 2) void scan_kernel(
    const _Float16* __restrict__ x0, const _Float16* __restrict__ c0,
    const float* __restrict__ c_sq, float* __restrict__ dm) {
  __shared__ __align__(16) _Float16 As0[65536];   // 131072 B

  const int b = blockIdx.x;
  const int kc = (b & 7) | ((b >> 4) & 8);   // blocks sharing a strip land on one XCD
  const int qb = (b >> 3) & 15;
  const int tid = (int)threadIdx.x;
  const int lane = tid & 63, w = tid >> 6;
  const int col = lane & 15, quad = lane >> 4;
  const int qrow0 = qb * QT;

#pragma unroll
  for (int i = 0; i < 16; ++i) {
    int u = i * 512 + tid;                   // 0..8191 (16B chunks)
    int kt = u >> 10, q = (u >> 8) & 3, r = u & 255;
    gl_lds16(x0 + (size_t)(qrow0 + r) * DDIM + kt * 32 + q * 8, As0 + (size_t)u * 8);
  }
  __syncthreads();   // only barrier

  for (int ct = 0; ct < STSZ / 256; ++ct) {
    const int cbase = kc * STSZ + ct * 256 + w * 32;   // wave-private 32-c slice
    f32x4 acc[16][2];
#pragma unroll
    for (int mt = 0; mt < 16; ++mt) { acc[mt][0] = (f32x4)0.0f; acc[mt][1] = (f32x4)0.0f; }

    for (int kt = 0; kt < 8; ++kt) {
      half8 b0f[2];
#pragma unroll
      for (int nt = 0; nt < 2; ++nt)
        b0f[nt] = *(const half8*)(c0 + (size_t)(cbase + nt * 16 + col) * DDIM + kt * 32 + quad * 8);
#pragma unroll
      for (int mt = 0; mt < 16; ++mt) {
        half8 a0f = *(const half8*)(As0 + (((kt * 4 + quad) * QT) + mt * 16 + col) * 8);
        acc[mt][0] = __builtin_amdgcn_mfma_f32_16x16x32_f16(a0f, b0f[0], acc[mt][0], 0, 0, 0);
        acc[mt][1] = __builtin_amdgcn_mfma_f32_16x16x32_f16(a0f, b0f[1], acc[mt][1], 0, 0, 0);
      }
    }

    const float cs0 = c_sq[cbase + col];
    const float cs1 = c_sq[cbase + 16 + col];
    const int grp = (kc * 16 + ct) * 8 + w;
    float* dmg = dm + (size_t)grp * 4096 + qrow0;
#pragma unroll
    for (int mt = 0; mt < 16; ++mt) {
      float m[4];
#pragma unroll
      for (int rg = 0; rg < 4; ++rg)
        m[rg] = fminf(fmaf(-2.0f, acc[mt][0][rg], cs0), fmaf(-2.0f, acc[mt][1][rg], cs1));
#pragma unroll
      for (int off = 1; off < 16; off <<= 1) {
#pragma unroll
        for (int rg = 0; rg < 4; ++rg) m[rg] = fminf(m[rg], __shfl_xor(m[rg], off, 64));
      }
      if (col == 0) {
        float4 vv = {m[0], m[1], m[2], m[3]};
        *(float4*)(dmg + mt * 16 + quad * 4) = vv;
      }
    }
  }
}

// ---------------- pmin: partial column-min of dm ----------------
__global__ __launch_bounds__(256) void pmin_kernel(const float* __restrict__ dm,
                                                   float* __restrict__ pm) {
  int qc = blockIdx.x & 15, gc = blockIdx.x >> 4;
  int q = qc * 256 + (int)threadIdx.x;
  float m = INFINITY;
  for (int g = gc * 128; g < gc * 128 + 128; ++g)
    m = fminf(m, dm[(size_t)g * 4096 + q]);
  pm[gc * 4096 + q] = m;
}

// ---------------- tq: per-query threshold + pk init ----------------
__global__ __launch_bounds__(256) void tq_kernel(const float* __restrict__ pm,
                                                 const float* __restrict__ x,
                                                 const unsigned* __restrict__ ctl,
                                                 float* __restrict__ T,
                                                 unsigned long long* __restrict__ pk) {
  int q = blockIdx.x * 256 + (int)threadIdx.x;
  float M = INFINITY;
#pragma unroll
  for (int i = 0; i < 16; ++i) M = fminf(M, pm[i * 4096 + q]);
  float xsq = 0.f;
  const float4* xr = (const float4*)(x + (size_t)q * DDIM);
#pragma unroll 8
  for (int i = 0; i < 64; ++i) {
    float4 v = xr[i];
    xsq = fmaf(v.x, v.x, fmaf(v.y, v.y, fmaf(v.z, v.z, fmaf(v.w, v.w, xsq))));
  }
  float cmaxsq = __uint_as_float(ctl[32]);
  // rigorous bound: 2 * 2^-9 ||x|| ||c||max; margin = 2x that + 1.0 absolute slack
  T[q] = M + 0.0078125f * sqrtf(xsq * cmaxsq) + 1.0f;
  pk[q] = 0xFFFFFFFFFFFFFFFFull;
}

// ---------------- emit: (q, group) pairs under threshold ----------------
__global__ __launch_bounds__(256) void emit_kernel(const float* __restrict__ dm,
                                                   const float* __restrict__ T,
                                                   unsigned* __restrict__ ctl,
                                                   unsigned* __restrict__ pairs) {
  int qc = blockIdx.x & 15, gc = blockIdx.x >> 4;
  int q = qc * 256 + (int)threadIdx.x;
  float t = T[q];
  for (int g = gc * 128; g < gc * 128 + 128; ++g)
    if (dm[(size_t)g * 4096 + q] <= t) {
      unsigned pos = atomicAdd(&ctl[0], 1u);
      if (pos < CAP) pairs[pos] = ((unsigned)g << 12) | (unsigned)q;
    }
}

// ---------------- rescore: exact f32 over each selected 32-c group ----------------
__global__ __launch_bounds__(256) void rescore_kernel(
    const unsigned* __restrict__ pairs, const unsigned* __restrict__ ctl,
    const float* __restrict__ x, const float* __restrict__ cent,
    const float* __restrict__ c_sq, unsigned long long* __restrict__ pk) {
  int W = blockIdx.x * 4 + ((int)threadIdx.x >> 6);
  int lane = (int)threadIdx.x & 63;
  int cnt = (int)ctl[0];
  if (cnt > CAP) cnt = CAP;
  for (int p = W; p < cnt; p += 4096) {
    unsigned pr = pairs[p];
    int q = (int)(pr & 4095u), grp = (int)(pr >> 12);
    int cb = (grp >> 3) * 256 + (grp & 7) * 32;
    int c = cb + (lane >> 1);
    int dh = (lane & 1) * 128;
    const float4* xr = (const float4*)(x + (size_t)q * DDIM + dh);
    const float4* cr = (const float4*)(cent + (size_t)c * DDIM + dh);
    float s = 0.f;
#pragma unroll
    for (int i = 0; i < 32; ++i) {
      float4 a = xr[i], bb = cr[i];
      s = fmaf(a.x, bb.x, fmaf(a.y, bb.y, fmaf(a.z, bb.z, fmaf(a.w, bb.w, s))));
    }
    s += __shfl_xor(s, 1, 64);
    float d = (lane & 1) ? INFINITY : fmaf(-2.0f, s, c_sq[c]);
    unsigned long long pkv = ((unsigned long long)fkey(d) << 32) | (unsigned)c;
#pragma unroll
    for (int off = 1; off < 64; off <<= 1) {
      unsigned long long o = __shfl_xor(pkv, off, 64);
      if (o < pkv) pkv = o;
    }
    if (lane == 0) atomicMin(&pk[q], pkv);
  }
}

// ---------------- final: gather winner (+ exact brute-force fallback) ----------------
__global__ __launch_bounds__(256) void final_kernel(const unsigned long long* __restrict__ pk,
                                                    const float* __restrict__ x,
                                                    const float* __restrict__ cent,
                                                    const float* __restrict__ c_sq,
                                                    float* __restrict__ out) {
  int q = blockIdx.x * 4 + ((int)threadIdx.x >> 6);
  int lane = (int)threadIdx.x & 63;
  unsigned long long e = pk[q];
  int idx;
  if (e != 0xFFFFFFFFFFFFFFFFull) {
    idx = (int)(unsigned)(e & 0xFFFFFFFFu);
  } else {
    // safety net: exact argmin over all 65536 centroids (should never trigger)
    const float4* xr = (const float4*)(x + (size_t)q * DDIM);
    unsigned long long best = 0xFFFFFFFFFFFFFFFFull;
    for (int c = lane; c < 65536; c += 64) {
      const float4* cr = (const float4*)(cent + (size_t)c * DDIM);
      float s = 0.f;
#pragma unroll 16
      for (int i = 0; i < 64; ++i) {
        float4 a = xr[i], bb = cr[i];
        s = fmaf(a.x, bb.x, fmaf(a.y, bb.y, fmaf(a.z, bb.z, fmaf(a.w, bb.w, s))));
      }
      float d = fmaf(-2.0f, s, c_sq[c]);
      unsigned long long pkv = ((unsigned long long)fkey(d) << 32) | (unsigned)c;
      if (pkv < best) best = pkv;
    }
#pragma unroll
    for (int off = 1; off < 64; off <<= 1) {
      unsigned long long o = __shfl_xor(best, off, 64);
      if (o < best) best = o;
    }
    idx = (int)(unsigned)(best & 0xFFFFFFFFu);
  }
  float4 v = ((const float4*)cent)[(size_t)idx * 64 + lane];
  ((float4*)out)[(size_t)q * 64 + lane] = v;
  if (lane == 0) out[(size_t)4096 * DDIM + q] = (float)idx;
}

extern "C" void kernel_launch(void* const* d_in, const int* in_sizes, int n_in,
                              void* d_out, int out_size, void* d_ws, size_t ws_size,
                              hipStream_t stream) {
  const float* x    = (const float*)d_in[1];   // [4096,256]
  const float* cent = (const float*)d_in[2];   // [65536,256]
  float* out = (float*)d_out;
  char* ws = (char*)d_ws;

  const size_t OFF_C0    = 0;           // 33,554,432  f16 hi(centroids)
  const size_t OFF_X0    = 33554432;    //  2,097,152  f16 hi(x)
  const size_t OFF_CSQ   = 35651584;    //    262,144
  const size_t OFF_CTL   = 35913728;    //        256
  const size_t OFF_DM    = 35913984;    // 33,554,432  f32[2048][4096]
  const size_t OFF_PM    = 69468416;    //    262,144  f32[16][4096]
  const size_t OFF_T     = 69730560;    //     16,384
  const size_t OFF_PK    = 69746944;    //     32,768  u64[4096]
  const size_t OFF_PAIRS = 69779712;    //  2,097,152  u32[524288] -> ends 71,876,864
  const size_t NEED      = 72089600;    // proven available since round 2
  if (ws_size < NEED) return;

  _Float16* c0 = (_Float16*)(ws + OFF_C0);
  _Float16* x0 = (_Float16*)(ws + OFF_X0);
  float* c_sq = (float*)(ws + OFF_CSQ);
  unsigned* ctl = (unsigned*)(ws + OFF_CTL);
  float* dm = (float*)(ws + OFF_DM);
  float* pm = (float*)(ws + OFF_PM);
  float* T  = (float*)(ws + OFF_T);
  unsigned long long* pk = (unsigned long long*)(ws + OFF_PK);
  unsigned* pairs = (unsigned*)(ws + OFF_PAIRS);

  initctl_kernel<<<1, 64, 0, stream>>>(ctl);
  splitx_kernel<<<16384, 256, 0, stream>>>(cent, c0, 65536 * 256 / 4);
  splitx_kernel<<<1024, 256, 0, stream>>>(x, x0, 4096 * 256 / 4);
  csq_kernel<<<16384, 256, 0, stream>>>(cent, c_sq, ctl);
  scan_kernel<<<256, 512, 0, stream>>>(x0, c0, c_sq, dm);
  pmin_kernel<<<256, 256, 0, stream>>>(dm, pm);
  tq_kernel<<<16, 256, 0, stream>>>(pm, x, ctl, T, pk);
  emit_kernel<<<256, 256, 0, stream>>>(dm, T, ctl, pairs);
  rescore_kernel<<<1024, 256, 0, stream>>>(pairs, ctl, x, cent, c_sq, pk);
  final_kernel<<<1024, 256, 0, stream>>>(pk, x, cent, c_sq, out);
}

// Round 10
// 1225.356 us; speedup vs baseline: 1.5148x; 1.5148x over previous
//
#include <hip/hip_runtime.h>
#include <hip/hip_bf16.h>
#include <math.h>

// B=4096 queries, D=256, K=65536 centroids (f32).
// Round 10: round-7's proven scan skeleton (grid (qb,kc) natural, QTILE=128, 512 thr,
// A hi-split persistent in 64KB LDS, wave owns 128q x 64c, 4 B-loads/kt) reduced to
// 1-term f16 MFMA, + per-ct 32c-group-min epilogue into dm. Decision pipeline from
// validated round 9: pmin -> tq (rigorous margin) -> emit -> exact f32 rescore with
// order-exact fkey packing -> final gather with brute-force fallback (also on overflow).

#define DDIM 256
#define QTILE 128
#define STSZ 8192      // centroids per strip (8 strips)
#define CAP 524288
#define F16_MINN 6.103515625e-5f

typedef __attribute__((ext_vector_type(8))) _Float16 half8;
typedef __attribute__((ext_vector_type(4))) _Float16 half4;
typedef __attribute__((ext_vector_type(4))) float f32x4;

__device__ __forceinline__ void gl_lds16(const void* g, void* l) {
  __builtin_amdgcn_global_load_lds((const __attribute__((address_space(1))) void*)g,
                                   (__attribute__((address_space(3))) void*)l, 16, 0, 0);
}

// exact order-preserving float -> uint key (finite floats; matches f32 <)
__device__ __forceinline__ unsigned fkey(float d) {
  unsigned ud = __float_as_uint(d);
  return ud ^ (((int)ud < 0) ? 0xFFFFFFFFu : 0x80000000u);
}

// ---------------- ctl init: [0]=pair count, [32]=cmax_sq bits ----------------
__global__ void initctl_kernel(unsigned* __restrict__ ctl) {
  if (threadIdx.x < 64) ctl[threadIdx.x] = 0u;
}

// ---------------- hi split: f32 -> f16 (subnormals clamped to 0) ----------------
__global__ __launch_bounds__(256) void splitx_kernel(const float* __restrict__ in,
                                                     _Float16* __restrict__ o0, int n4) {
  int i = blockIdx.x * 256 + threadIdx.x;
  if (i >= n4) return;
  float4 v = ((const float4*)in)[i];
  float vv[4] = {v.x, v.y, v.z, v.w};
  half4 h0;
#pragma unroll
  for (int e = 0; e < 4; ++e)
    h0[e] = (fabsf(vv[e]) < F16_MINN) ? (_Float16)0.f : (_Float16)vv[e];
  *(half4*)(o0 + (size_t)i * 4) = h0;
}

// ---------------- c_sq (exact f32) + max ||c||^2 ----------------
__global__ __launch_bounds__(256) void csq_kernel(const float* __restrict__ cent,
                                                  float* __restrict__ c_sq,
                                                  unsigned* __restrict__ ctl) {
  int gtid = blockIdx.x * 256 + threadIdx.x;
  int c = gtid >> 6;
  int lane = threadIdx.x & 63;
  float4 v = ((const float4*)(cent + (size_t)c * DDIM))[lane];
  float s = v.x * v.x + v.y * v.y + v.z * v.z + v.w * v.w;
#pragma unroll
  for (int off = 32; off > 0; off >>= 1) s += __shfl_down(s, off, 64);
  if (lane == 0) {
    c_sq[c] = s;
    atomicMax(&ctl[32], __float_as_uint(s));  // positive floats: uint order == float order
  }
}

// ---------------- scan: 1-term f16 MFMA, min per (q, 32c-group) ----------------
// Grid (32 qb, 8 kc) natural order (round-7 proven). Block: 512 thr / 8 waves,
// 128 q x 8192 c strip. Wave w owns c-slice [w*64,(w+1)*64) of each 512-c subtile.
// A LDS: [kt 8][quad 4][row 128][8 f16]. grp = c_base/32.
__global__ __launch_bounds__(512, 2) void scan_kernel(
    const _Float16* __restrict__ x0, const _Float16* __restrict__ c0,
    const float* __restrict__ c_sq, float* __restrict__ dm) {
  __shared__ __align__(16) _Float16 As0[32768];   // 64 KiB

  const int qb = blockIdx.x, kc = blockIdx.y;
  const int tid = (int)threadIdx.x;
  const int lane = tid & 63, w = tid >> 6;
  const int col = lane & 15, quad = lane >> 4;
  const int qrow0 = qb * QTILE;

  // ---- stage A once: 128 rows x 256 k hi-split (r7-identical pattern) ----
#pragma unroll
  for (int i = 0; i < 8; ++i) {
    int u = i * 512 + tid;                 // 0..4095 (16B chunks)
    int kt = u >> 9, q = (u >> 7) & 3, r = u & 127;
    gl_lds16(x0 + (size_t)(qrow0 + r) * DDIM + kt * 32 + q * 8, As0 + (size_t)u * 8);
  }
  __syncthreads();   // only barrier

  for (int ct = 0; ct < STSZ / 512; ++ct) {
    const int cbase = kc * STSZ + ct * 512 + w * 64;   // wave-private 64-c slice
    f32x4 acc[8][4];
#pragma unroll
    for (int mt = 0; mt < 8; ++mt)
#pragma unroll
      for (int nt = 0; nt < 4; ++nt) acc[mt][nt] = (f32x4)0.0f;

#pragma unroll 2
    for (int kt = 0; kt < 8; ++kt) {
      const int k0 = kt * 32;
      half8 b0f[4];
#pragma unroll
      for (int nt = 0; nt < 4; ++nt)
        b0f[nt] = *(const half8*)(c0 + (size_t)(cbase + nt * 16 + col) * DDIM + k0 + quad * 8);
#pragma unroll
      for (int mt = 0; mt < 8; ++mt) {
        half8 a0f = *(const half8*)(As0 + (((kt * 4 + quad) * QTILE) + mt * 16 + col) * 8);
#pragma unroll
        for (int nt = 0; nt < 4; ++nt)
          acc[mt][nt] = __builtin_amdgcn_mfma_f32_16x16x32_f16(a0f, b0f[nt], acc[mt][nt], 0, 0, 0);
      }
    }

    // epilogue: per 32c-half h: d = cs - 2*dot, min over {nt pair, col}, dense store
    const int grpb = (kc * 16 + ct) * 16 + w * 2;      // grp = c_base/32
    float cs[4];
#pragma unroll
    for (int nt = 0; nt < 4; ++nt) cs[nt] = c_sq[cbase + nt * 16 + col];
#pragma unroll
    for (int h = 0; h < 2; ++h) {
      float* dmg = dm + (size_t)(grpb + h) * 4096 + qrow0;
#pragma unroll
      for (int mt = 0; mt < 8; ++mt) {
        float m[4];
#pragma unroll
        for (int rg = 0; rg < 4; ++rg)
          m[rg] = fminf(fmaf(-2.0f, acc[mt][2 * h][rg], cs[2 * h]),
                        fmaf(-2.0f, acc[mt][2 * h + 1][rg], cs[2 * h + 1]));
#pragma unroll
        for (int off = 1; off < 16; off <<= 1) {
#pragma unroll
          for (int rg = 0; rg < 4; ++rg) m[rg] = fminf(m[rg], __shfl_xor(m[rg], off, 64));
        }
        // all lanes now hold the col-min; 16 lanes (col<4) store 64 B dense
        float v = (col & 1) ? ((col & 2) ? m[3] : m[1]) : ((col & 2) ? m[2] : m[0]);
        if (col < 4) dmg[mt * 16 + quad * 4 + (col & 3)] = v;
      }
    }
  }
}

// ---------------- pmin: partial column-min of dm ----------------
__global__ __launch_bounds__(256) void pmin_kernel(const float* __restrict__ dm,
                                                   float* __restrict__ pm) {
  int qc = blockIdx.x & 15, gc = blockIdx.x >> 4;
  int q = qc * 256 + (int)threadIdx.x;
  float m = INFINITY;
  for (int g = gc * 128; g < gc * 128 + 128; ++g)
    m = fminf(m, dm[(size_t)g * 4096 + q]);
  pm[gc * 4096 + q] = m;
}

// ---------------- tq: per-query threshold + pk init ----------------
__global__ __launch_bounds__(256) void tq_kernel(const float* __restrict__ pm,
                                                 const float* __restrict__ x,
                                                 const unsigned* __restrict__ ctl,
                                                 float* __restrict__ T,
                                                 unsigned long long* __restrict__ pk) {
  int q = blockIdx.x * 256 + (int)threadIdx.x;
  float M = INFINITY;
#pragma unroll
  for (int i = 0; i < 16; ++i) M = fminf(M, pm[i * 4096 + q]);
  float xsq = 0.f;
  const float4* xr = (const float4*)(x + (size_t)q * DDIM);
#pragma unroll 8
  for (int i = 0; i < 64; ++i) {
    float4 v = xr[i];
    xsq = fmaf(v.x, v.x, fmaf(v.y, v.y, fmaf(v.z, v.z, fmaf(v.w, v.w, xsq))));
  }
  float cmaxsq = __uint_as_float(ctl[32]);
  // rigorous 1-term f16 bound ~2^-9 ||x|| ||c||max; margin = 4x bound + 1.0 slack
  T[q] = M + 0.0078125f * sqrtf(xsq * cmaxsq) + 1.0f;
  pk[q] = 0xFFFFFFFFFFFFFFFFull;
}

// ---------------- emit: (q, group) pairs under threshold ----------------
__global__ __launch_bounds__(256) void emit_kernel(const float* __restrict__ dm,
                                                   const float* __restrict__ T,
                                                   unsigned* __restrict__ ctl,
                                                   unsigned* __restrict__ pairs) {
  int qc = blockIdx.x & 15, gc = blockIdx.x >> 4;
  int q = qc * 256 + (int)threadIdx.x;
  float t = T[q];
  for (int g = gc * 128; g < gc * 128 + 128; ++g)
    if (dm[(size_t)g * 4096 + q] <= t) {
      unsigned pos = atomicAdd(&ctl[0], 1u);
      if (pos < CAP) pairs[pos] = ((unsigned)g << 12) | (unsigned)q;
    }
}

// ---------------- rescore: exact f32 over each selected 32-c group ----------------
__global__ __launch_bounds__(256) void rescore_kernel(
    const unsigned* __restrict__ pairs, const unsigned* __restrict__ ctl,
    const float* __restrict__ x, const float* __restrict__ cent,
    const float* __restrict__ c_sq, unsigned long long* __restrict__ pk) {
  int W = blockIdx.x * 4 + ((int)threadIdx.x >> 6);
  int lane = (int)threadIdx.x & 63;
  int cnt = (int)ctl[0];
  if (cnt > CAP) cnt = CAP;
  for (int p = W; p < cnt; p += 4096) {
    unsigned pr = pairs[p];
    int q = (int)(pr & 4095u), grp = (int)(pr >> 12);
    int c = grp * 32 + (lane >> 1);
    int dh = (lane & 1) * 128;
    const float4* xr = (const float4*)(x + (size_t)q * DDIM + dh);
    const float4* cr = (const float4*)(cent + (size_t)c * DDIM + dh);
    float s = 0.f;
#pragma unroll
    for (int i = 0; i < 32; ++i) {
      float4 a = xr[i], bb = cr[i];
      s = fmaf(a.x, bb.x, fmaf(a.y, bb.y, fmaf(a.z, bb.z, fmaf(a.w, bb.w, s))));
    }
    s += __shfl_xor(s, 1, 64);
    float d = (lane & 1) ? INFINITY : fmaf(-2.0f, s, c_sq[c]);
    unsigned long long pkv = ((unsigned long long)fkey(d) << 32) | (unsigned)c;
#pragma unroll
    for (int off = 1; off < 64; off <<= 1) {
      unsigned long long o = __shfl_xor(pkv, off, 64);
      if (o < pkv) pkv = o;
    }
    if (lane == 0) atomicMin(&pk[q], pkv);
  }
}

// ---------------- final: gather winner (+ exact fallback, also on overflow) ----------
__global__ __launch_bounds__(256) void final_kernel(const unsigned long long* __restrict__ pk,
                                                    const unsigned* __restrict__ ctl,
                                                    const float* __restrict__ x,
                                                    const float* __restrict__ cent,
                                                    const float* __restrict__ c_sq,
                                                    float* __restrict__ out) {
  int q = blockIdx.x * 4 + ((int)threadIdx.x >> 6);
  int lane = (int)threadIdx.x & 63;
  unsigned long long e = pk[q];
  bool overflow = ctl[0] > CAP;
  int idx;
  if (e != 0xFFFFFFFFFFFFFFFFull && !overflow) {
    idx = (int)(unsigned)(e & 0xFFFFFFFFu);
  } else {
    // safety net: exact argmin over all 65536 centroids (should never trigger)
    const float4* xr = (const float4*)(x + (size_t)q * DDIM);
    unsigned long long best = 0xFFFFFFFFFFFFFFFFull;
    for (int c = lane; c < 65536; c += 64) {
      const float4* cr = (const float4*)(cent + (size_t)c * DDIM);
      float s = 0.f;
#pragma unroll 16
      for (int i = 0; i < 64; ++i) {
        float4 a = xr[i], bb = cr[i];
        s = fmaf(a.x, bb.x, fmaf(a.y, bb.y, fmaf(a.z, bb.z, fmaf(a.w, bb.w, s))));
      }
      float d = fmaf(-2.0f, s, c_sq[c]);
      unsigned long long pkv = ((unsigned long long)fkey(d) << 32) | (unsigned)c;
      if (pkv < best) best = pkv;
    }
#pragma unroll
    for (int off = 1; off < 64; off <<= 1) {
      unsigned long long o = __shfl_xor(best, off, 64);
      if (o < best) best = o;
    }
    idx = (int)(unsigned)(best & 0xFFFFFFFFu);
  }
  float4 v = ((const float4*)cent)[(size_t)idx * 64 + lane];
  ((float4*)out)[(size_t)q * 64 + lane] = v;
  if (lane == 0) out[(size_t)4096 * DDIM + q] = (float)idx;
}

extern "C" void kernel_launch(void* const* d_in, const int* in_sizes, int n_in,
                              void* d_out, int out_size, void* d_ws, size_t ws_size,
                              hipStream_t stream) {
  const float* x    = (const float*)d_in[1];   // [4096,256]
  const float* cent = (const float*)d_in[2];   // [65536,256]
  float* out = (float*)d_out;
  char* ws = (char*)d_ws;

  const size_t OFF_C0    = 0;           // 33,554,432  f16 hi(centroids)
  const size_t OFF_X0    = 33554432;    //  2,097,152  f16 hi(x)
  const size_t OFF_CSQ   = 35651584;    //    262,144
  const size_t OFF_CTL   = 35913728;    //        256
  const size_t OFF_DM    = 35913984;    // 33,554,432  f32[2048][4096]
  const size_t OFF_PM    = 69468416;    //    262,144  f32[16][4096]
  const size_t OFF_T     = 69730560;    //     16,384
  const size_t OFF_PK    = 69746944;    //     32,768  u64[4096]
  const size_t OFF_PAIRS = 69779712;    //  2,097,152  u32[524288]
  const size_t NEED      = 72089600;    // proven available since round 2
  if (ws_size < NEED) return;

  _Float16* c0 = (_Float16*)(ws + OFF_C0);
  _Float16* x0 = (_Float16*)(ws + OFF_X0);
  float* c_sq = (float*)(ws + OFF_CSQ);
  unsigned* ctl = (unsigned*)(ws + OFF_CTL);
  float* dm = (float*)(ws + OFF_DM);
  float* pm = (float*)(ws + OFF_PM);
  float* T  = (float*)(ws + OFF_T);
  unsigned long long* pk = (unsigned long long*)(ws + OFF_PK);
  unsigned* pairs = (unsigned*)(ws + OFF_PAIRS);

  initctl_kernel<<<1, 64, 0, stream>>>(ctl);
  splitx_kernel<<<16384, 256, 0, stream>>>(cent, c0, 65536 * 256 / 4);
  splitx_kernel<<<1024, 256, 0, stream>>>(x, x0, 4096 * 256 / 4);
  csq_kernel<<<16384, 256, 0, stream>>>(cent, c_sq, ctl);
  scan_kernel<<<dim3(32, 8), 512, 0, stream>>>(x0, c0, c_sq, dm);
  pmin_kernel<<<256, 256, 0, stream>>>(dm, pm);
  tq_kernel<<<16, 256, 0, stream>>>(pm, x, ctl, T, pk);
  emit_kernel<<<256, 256, 0, stream>>>(dm, T, ctl, pairs);
  rescore_kernel<<<1024, 256, 0, stream>>>(pairs, ctl, x, cent, c_sq, pk);
  final_kernel<<<1024, 256, 0, stream>>>(pk, ctl, x, cent, c_sq, out);
}

// Round 11
// 483.060 us; speedup vs baseline: 3.8425x; 2.5367x over previous
//
#include <hip/hip_runtime.h>
#include <hip/hip_bf16.h>
#include <math.h>

// B=4096 queries, D=256, K=65536 centroids (f32).
// Round 11: round-10 pipeline unchanged EXCEPT csq's 65536 same-address atomicMax
// (measured 746 us of serialized atomics) replaced by plain stores + a 2-stage
// cmax reduction (64 atomics total).
// Pipeline: 1-term f16 MFMA scan -> per-(q,32c-group) min (dense dm) -> pmin ->
// tq (rigorous margin) -> emit -> exact f32 rescore (order-exact fkey, u64 atomicMin)
// -> final gather with brute-force fallback (also on overflow).

#define DDIM 256
#define QTILE 128
#define STSZ 8192      // centroids per strip (8 strips)
#define CAP 524288
#define F16_MINN 6.103515625e-5f

typedef __attribute__((ext_vector_type(8))) _Float16 half8;
typedef __attribute__((ext_vector_type(4))) _Float16 half4;
typedef __attribute__((ext_vector_type(4))) float f32x4;

__device__ __forceinline__ void gl_lds16(const void* g, void* l) {
  __builtin_amdgcn_global_load_lds((const __attribute__((address_space(1))) void*)g,
                                   (__attribute__((address_space(3))) void*)l, 16, 0, 0);
}

// exact order-preserving float -> uint key (finite floats; matches f32 <)
__device__ __forceinline__ unsigned fkey(float d) {
  unsigned ud = __float_as_uint(d);
  return ud ^ (((int)ud < 0) ? 0xFFFFFFFFu : 0x80000000u);
}

// ---------------- ctl init: [0]=pair count, [32]=cmax_sq bits ----------------
__global__ void initctl_kernel(unsigned* __restrict__ ctl) {
  if (threadIdx.x < 64) ctl[threadIdx.x] = 0u;
}

// ---------------- hi split: f32 -> f16 (subnormals clamped to 0) ----------------
__global__ __launch_bounds__(256) void splitx_kernel(const float* __restrict__ in,
                                                     _Float16* __restrict__ o0, int n4) {
  int i = blockIdx.x * 256 + threadIdx.x;
  if (i >= n4) return;
  float4 v = ((const float4*)in)[i];
  float vv[4] = {v.x, v.y, v.z, v.w};
  half4 h0;
#pragma unroll
  for (int e = 0; e < 4; ++e)
    h0[e] = (fabsf(vv[e]) < F16_MINN) ? (_Float16)0.f : (_Float16)vv[e];
  *(half4*)(o0 + (size_t)i * 4) = h0;
}

// ---------------- c_sq (exact f32), NO atomics ----------------
__global__ __launch_bounds__(256) void csq_kernel(const float* __restrict__ cent,
                                                  float* __restrict__ c_sq) {
  int gtid = blockIdx.x * 256 + threadIdx.x;
  int c = gtid >> 6;
  int lane = threadIdx.x & 63;
  float4 v = ((const float4*)(cent + (size_t)c * DDIM))[lane];
  float s = v.x * v.x + v.y * v.y + v.z * v.z + v.w * v.w;
#pragma unroll
  for (int off = 32; off > 0; off >>= 1) s += __shfl_down(s, off, 64);
  if (lane == 0) c_sq[c] = s;
}

// ---------------- cmax: 2-stage max of c_sq, one atomic per block (64 total) --------
__global__ __launch_bounds__(256) void cmax_kernel(const float* __restrict__ c_sq,
                                                   unsigned* __restrict__ ctl) {
  __shared__ float red[4];
  int t = blockIdx.x * 256 + (int)threadIdx.x;     // 16384 threads x 4 values
  float4 v = ((const float4*)c_sq)[t];
  float m = fmaxf(fmaxf(v.x, v.y), fmaxf(v.z, v.w));
#pragma unroll
  for (int off = 32; off > 0; off >>= 1) m = fmaxf(m, __shfl_down(m, off, 64));
  int lane = (int)threadIdx.x & 63, w = (int)threadIdx.x >> 6;
  if (lane == 0) red[w] = m;
  __syncthreads();
  if (threadIdx.x == 0) {
    m = fmaxf(fmaxf(red[0], red[1]), fmaxf(red[2], red[3]));
    atomicMax(&ctl[32], __float_as_uint(m));  // positive: uint order == float order
  }
}

// ---------------- scan: 1-term f16 MFMA, min per (q, 32c-group) ----------------
// Grid (32 qb, 8 kc) natural order (round-7 proven). Block: 512 thr / 8 waves,
// 128 q x 8192 c strip. Wave w owns c-slice [w*64,(w+1)*64) of each 512-c subtile.
// A LDS: [kt 8][quad 4][row 128][8 f16]. grp = c_base/32.
__global__ __launch_bounds__(512, 2) void scan_kernel(
    const _Float16* __restrict__ x0, const _Float16* __restrict__ c0,
    const float* __restrict__ c_sq, float* __restrict__ dm) {
  __shared__ __align__(16) _Float16 As0[32768];   // 64 KiB

  const int qb = blockIdx.x, kc = blockIdx.y;
  const int tid = (int)threadIdx.x;
  const int lane = tid & 63, w = tid >> 6;
  const int col = lane & 15, quad = lane >> 4;
  const int qrow0 = qb * QTILE;

#pragma unroll
  for (int i = 0; i < 8; ++i) {
    int u = i * 512 + tid;                 // 0..4095 (16B chunks)
    int kt = u >> 9, q = (u >> 7) & 3, r = u & 127;
    gl_lds16(x0 + (size_t)(qrow0 + r) * DDIM + kt * 32 + q * 8, As0 + (size_t)u * 8);
  }
  __syncthreads();   // only barrier

  for (int ct = 0; ct < STSZ / 512; ++ct) {
    const int cbase = kc * STSZ + ct * 512 + w * 64;   // wave-private 64-c slice
    f32x4 acc[8][4];
#pragma unroll
    for (int mt = 0; mt < 8; ++mt)
#pragma unroll
      for (int nt = 0; nt < 4; ++nt) acc[mt][nt] = (f32x4)0.0f;

#pragma unroll 2
    for (int kt = 0; kt < 8; ++kt) {
      const int k0 = kt * 32;
      half8 b0f[4];
#pragma unroll
      for (int nt = 0; nt < 4; ++nt)
        b0f[nt] = *(const half8*)(c0 + (size_t)(cbase + nt * 16 + col) * DDIM + k0 + quad * 8);
#pragma unroll
      for (int mt = 0; mt < 8; ++mt) {
        half8 a0f = *(const half8*)(As0 + (((kt * 4 + quad) * QTILE) + mt * 16 + col) * 8);
#pragma unroll
        for (int nt = 0; nt < 4; ++nt)
          acc[mt][nt] = __builtin_amdgcn_mfma_f32_16x16x32_f16(a0f, b0f[nt], acc[mt][nt], 0, 0, 0);
      }
    }

    // epilogue: per 32c-half h: d = cs - 2*dot, min over {nt pair, col}, dense store
    const int grpb = (kc * 16 + ct) * 16 + w * 2;      // grp = c_base/32
    float cs[4];
#pragma unroll
    for (int nt = 0; nt < 4; ++nt) cs[nt] = c_sq[cbase + nt * 16 + col];
#pragma unroll
    for (int h = 0; h < 2; ++h) {
      float* dmg = dm + (size_t)(grpb + h) * 4096 + qrow0;
#pragma unroll
      for (int mt = 0; mt < 8; ++mt) {
        float m[4];
#pragma unroll
        for (int rg = 0; rg < 4; ++rg)
          m[rg] = fminf(fmaf(-2.0f, acc[mt][2 * h][rg], cs[2 * h]),
                        fmaf(-2.0f, acc[mt][2 * h + 1][rg], cs[2 * h + 1]));
#pragma unroll
        for (int off = 1; off < 16; off <<= 1) {
#pragma unroll
          for (int rg = 0; rg < 4; ++rg) m[rg] = fminf(m[rg], __shfl_xor(m[rg], off, 64));
        }
        float v = (col & 1) ? ((col & 2) ? m[3] : m[1]) : ((col & 2) ? m[2] : m[0]);
        if (col < 4) dmg[mt * 16 + quad * 4 + (col & 3)] = v;
      }
    }
  }
}

// ---------------- pmin: partial column-min of dm ----------------
__global__ __launch_bounds__(256) void pmin_kernel(const float* __restrict__ dm,
                                                   float* __restrict__ pm) {
  int qc = blockIdx.x & 15, gc = blockIdx.x >> 4;
  int q = qc * 256 + (int)threadIdx.x;
  float m = INFINITY;
  for (int g = gc * 128; g < gc * 128 + 128; ++g)
    m = fminf(m, dm[(size_t)g * 4096 + q]);
  pm[gc * 4096 + q] = m;
}

// ---------------- tq: per-query threshold + pk init ----------------
__global__ __launch_bounds__(256) void tq_kernel(const float* __restrict__ pm,
                                                 const float* __restrict__ x,
                                                 const unsigned* __restrict__ ctl,
                                                 float* __restrict__ T,
                                                 unsigned long long* __restrict__ pk) {
  int q = blockIdx.x * 256 + (int)threadIdx.x;
  float M = INFINITY;
#pragma unroll
  for (int i = 0; i < 16; ++i) M = fminf(M, pm[i * 4096 + q]);
  float xsq = 0.f;
  const float4* xr = (const float4*)(x + (size_t)q * DDIM);
#pragma unroll 8
  for (int i = 0; i < 64; ++i) {
    float4 v = xr[i];
    xsq = fmaf(v.x, v.x, fmaf(v.y, v.y, fmaf(v.z, v.z, fmaf(v.w, v.w, xsq))));
  }
  float cmaxsq = __uint_as_float(ctl[32]);
  // rigorous 1-term f16 bound ~2^-9 ||x|| ||c||max; margin = 4x bound + 1.0 slack
  T[q] = M + 0.0078125f * sqrtf(xsq * cmaxsq) + 1.0f;
  pk[q] = 0xFFFFFFFFFFFFFFFFull;
}

// ---------------- emit: (q, group) pairs under threshold ----------------
__global__ __launch_bounds__(256) void emit_kernel(const float* __restrict__ dm,
                                                   const float* __restrict__ T,
                                                   unsigned* __restrict__ ctl,
                                                   unsigned* __restrict__ pairs) {
  int qc = blockIdx.x & 15, gc = blockIdx.x >> 4;
  int q = qc * 256 + (int)threadIdx.x;
  float t = T[q];
  for (int g = gc * 128; g < gc * 128 + 128; ++g)
    if (dm[(size_t)g * 4096 + q] <= t) {
      unsigned pos = atomicAdd(&ctl[0], 1u);
      if (pos < CAP) pairs[pos] = ((unsigned)g << 12) | (unsigned)q;
    }
}

// ---------------- rescore: exact f32 over each selected 32-c group ----------------
__global__ __launch_bounds__(256) void rescore_kernel(
    const unsigned* __restrict__ pairs, const unsigned* __restrict__ ctl,
    const float* __restrict__ x, const float* __restrict__ cent,
    const float* __restrict__ c_sq, unsigned long long* __restrict__ pk) {
  int W = blockIdx.x * 4 + ((int)threadIdx.x >> 6);
  int lane = (int)threadIdx.x & 63;
  int cnt = (int)ctl[0];
  if (cnt > CAP) cnt = CAP;
  for (int p = W; p < cnt; p += 4096) {
    unsigned pr = pairs[p];
    int q = (int)(pr & 4095u), grp = (int)(pr >> 12);
    int c = grp * 32 + (lane >> 1);
    int dh = (lane & 1) * 128;
    const float4* xr = (const float4*)(x + (size_t)q * DDIM + dh);
    const float4* cr = (const float4*)(cent + (size_t)c * DDIM + dh);
    float s = 0.f;
#pragma unroll
    for (int i = 0; i < 32; ++i) {
      float4 a = xr[i], bb = cr[i];
      s = fmaf(a.x, bb.x, fmaf(a.y, bb.y, fmaf(a.z, bb.z, fmaf(a.w, bb.w, s))));
    }
    s += __shfl_xor(s, 1, 64);
    float d = (lane & 1) ? INFINITY : fmaf(-2.0f, s, c_sq[c]);
    unsigned long long pkv = ((unsigned long long)fkey(d) << 32) | (unsigned)c;
#pragma unroll
    for (int off = 1; off < 64; off <<= 1) {
      unsigned long long o = __shfl_xor(pkv, off, 64);
      if (o < pkv) pkv = o;
    }
    if (lane == 0) atomicMin(&pk[q], pkv);
  }
}

// ---------------- final: gather winner (+ exact fallback, also on overflow) ----------
__global__ __launch_bounds__(256) void final_kernel(const unsigned long long* __restrict__ pk,
                                                    const unsigned* __restrict__ ctl,
                                                    const float* __restrict__ x,
                                                    const float* __restrict__ cent,
                                                    const float* __restrict__ c_sq,
                                                    float* __restrict__ out) {
  int q = blockIdx.x * 4 + ((int)threadIdx.x >> 6);
  int lane = (int)threadIdx.x & 63;
  unsigned long long e = pk[q];
  bool overflow = ctl[0] > CAP;
  int idx;
  if (e != 0xFFFFFFFFFFFFFFFFull && !overflow) {
    idx = (int)(unsigned)(e & 0xFFFFFFFFu);
  } else {
    // safety net: exact argmin over all 65536 centroids (should never trigger)
    const float4* xr = (const float4*)(x + (size_t)q * DDIM);
    unsigned long long best = 0xFFFFFFFFFFFFFFFFull;
    for (int c = lane; c < 65536; c += 64) {
      const float4* cr = (const float4*)(cent + (size_t)c * DDIM);
      float s = 0.f;
#pragma unroll 16
      for (int i = 0; i < 64; ++i) {
        float4 a = xr[i], bb = cr[i];
        s = fmaf(a.x, bb.x, fmaf(a.y, bb.y, fmaf(a.z, bb.z, fmaf(a.w, bb.w, s))));
      }
      float d = fmaf(-2.0f, s, c_sq[c]);
      unsigned long long pkv = ((unsigned long long)fkey(d) << 32) | (unsigned)c;
      if (pkv < best) best = pkv;
    }
#pragma unroll
    for (int off = 1; off < 64; off <<= 1) {
      unsigned long long o = __shfl_xor(best, off, 64);
      if (o < best) best = o;
    }
    idx = (int)(unsigned)(best & 0xFFFFFFFFu);
  }
  float4 v = ((const float4*)cent)[(size_t)idx * 64 + lane];
  ((float4*)out)[(size_t)q * 64 + lane] = v;
  if (lane == 0) out[(size_t)4096 * DDIM + q] = (float)idx;
}

extern "C" void kernel_launch(void* const* d_in, const int* in_sizes, int n_in,
                              void* d_out, int out_size, void* d_ws, size_t ws_size,
                              hipStream_t stream) {
  const float* x    = (const float*)d_in[1];   // [4096,256]
  const float* cent = (const float*)d_in[2];   // [65536,256]
  float* out = (float*)d_out;
  char* ws = (char*)d_ws;

  const size_t OFF_C0    = 0;           // 33,554,432  f16 hi(centroids)
  const size_t OFF_X0    = 33554432;    //  2,097,152  f16 hi(x)
  const size_t OFF_CSQ   = 35651584;    //    262,144
  const size_t OFF_CTL   = 35913728;    //        256
  const size_t OFF_DM    = 35913984;    // 33,554,432  f32[2048][4096]
  const size_t OFF_PM    = 69468416;    //    262,144  f32[16][4096]
  const size_t OFF_T     = 69730560;    //     16,384
  const size_t OFF_PK    = 69746944;    //     32,768  u64[4096]
  const size_t OFF_PAIRS = 69779712;    //  2,097,152  u32[524288]
  const size_t NEED      = 72089600;    // proven available since round 2
  if (ws_size < NEED) return;

  _Float16* c0 = (_Float16*)(ws + OFF_C0);
  _Float16* x0 = (_Float16*)(ws + OFF_X0);
  float* c_sq = (float*)(ws + OFF_CSQ);
  unsigned* ctl = (unsigned*)(ws + OFF_CTL);
  float* dm = (float*)(ws + OFF_DM);
  float* pm = (float*)(ws + OFF_PM);
  float* T  = (float*)(ws + OFF_T);
  unsigned long long* pk = (unsigned long long*)(ws + OFF_PK);
  unsigned* pairs = (unsigned*)(ws + OFF_PAIRS);

  initctl_kernel<<<1, 64, 0, stream>>>(ctl);
  splitx_kernel<<<16384, 256, 0, stream>>>(cent, c0, 65536 * 256 / 4);
  splitx_kernel<<<1024, 256, 0, stream>>>(x, x0, 4096 * 256 / 4);
  csq_kernel<<<16384, 256, 0, stream>>>(cent, c_sq);
  cmax_kernel<<<64, 256, 0, stream>>>(c_sq, ctl);
  scan_kernel<<<dim3(32, 8), 512, 0, stream>>>(x0, c0, c_sq, dm);
  pmin_kernel<<<256, 256, 0, stream>>>(dm, pm);
  tq_kernel<<<16, 256, 0, stream>>>(pm, x, ctl, T, pk);
  emit_kernel<<<256, 256, 0, stream>>>(dm, T, ctl, pairs);
  rescore_kernel<<<1024, 256, 0, stream>>>(pairs, ctl, x, cent, c_sq, pk);
  final_kernel<<<1024, 256, 0, stream>>>(pk, ctl, x, cent, c_sq, out);
}

// Round 12
// 434.686 us; speedup vs baseline: 4.2701x; 1.1113x over previous
//
#include <hip/hip_runtime.h>
#include <hip/hip_bf16.h>
#include <math.h>

// B=4096 queries, D=256, K=65536 centroids (f32).
// Round 12: round-11 pipeline with two changes:
//  (1) scan MFMA transposed: mfma(centroid_frag, query_frag) -> centroids on C rows
//      (quad,rg), queries on C cols -> 32c group-min is 7 in-lane fmin + 2 shuffles
//      (was 4x 4-step shuffle trees). Loads/LDS/MFMA count identical to round 11.
//  (2) csq fused into the centroid split kernel (one wave = one row).
// Decision pipeline (dm/pmin/tq/emit/rescore/final) byte-identical to round 11.

#define DDIM 256
#define QTILE 128
#define STSZ 8192      // centroids per strip (8 strips)
#define CAP 524288
#define F16_MINN 6.103515625e-5f

typedef __attribute__((ext_vector_type(8))) _Float16 half8;
typedef __attribute__((ext_vector_type(4))) _Float16 half4;
typedef __attribute__((ext_vector_type(4))) float f32x4;

__device__ __forceinline__ void gl_lds16(const void* g, void* l) {
  __builtin_amdgcn_global_load_lds((const __attribute__((address_space(1))) void*)g,
                                   (__attribute__((address_space(3))) void*)l, 16, 0, 0);
}

// exact order-preserving float -> uint key (finite floats; matches f32 <)
__device__ __forceinline__ unsigned fkey(float d) {
  unsigned ud = __float_as_uint(d);
  return ud ^ (((int)ud < 0) ? 0xFFFFFFFFu : 0x80000000u);
}

// ---------------- ctl init: [0]=pair count, [32]=cmax_sq bits ----------------
__global__ void initctl_kernel(unsigned* __restrict__ ctl) {
  if (threadIdx.x < 64) ctl[threadIdx.x] = 0u;
}

// ---------------- centroid split + c_sq fused (one wave = one 256-elem row) --------
__global__ __launch_bounds__(256) void splitc_kernel(const float* __restrict__ in,
                                                     _Float16* __restrict__ o0,
                                                     float* __restrict__ c_sq) {
  int i = blockIdx.x * 256 + threadIdx.x;   // 4-elem chunk id; wave = one row
  int lane = (int)threadIdx.x & 63;
  float4 v = ((const float4*)in)[i];
  float vv[4] = {v.x, v.y, v.z, v.w};
  half4 h0;
#pragma unroll
  for (int e = 0; e < 4; ++e)
    h0[e] = (fabsf(vv[e]) < F16_MINN) ? (_Float16)0.f : (_Float16)vv[e];
  *(half4*)(o0 + (size_t)i * 4) = h0;
  float s = fmaf(v.x, v.x, fmaf(v.y, v.y, fmaf(v.z, v.z, v.w * v.w)));
#pragma unroll
  for (int off = 32; off > 0; off >>= 1) s += __shfl_down(s, off, 64);
  if (lane == 0) c_sq[i >> 6] = s;
}

// ---------------- x split: hi part only ----------------
__global__ __launch_bounds__(256) void splitx_kernel(const float* __restrict__ in,
                                                     _Float16* __restrict__ o0, int n4) {
  int i = blockIdx.x * 256 + threadIdx.x;
  if (i >= n4) return;
  float4 v = ((const float4*)in)[i];
  float vv[4] = {v.x, v.y, v.z, v.w};
  half4 h0;
#pragma unroll
  for (int e = 0; e < 4; ++e)
    h0[e] = (fabsf(vv[e]) < F16_MINN) ? (_Float16)0.f : (_Float16)vv[e];
  *(half4*)(o0 + (size_t)i * 4) = h0;
}

// ---------------- cmax: 2-stage max of c_sq, one atomic per block (64 total) --------
__global__ __launch_bounds__(256) void cmax_kernel(const float* __restrict__ c_sq,
                                                   unsigned* __restrict__ ctl) {
  __shared__ float red[4];
  int t = blockIdx.x * 256 + (int)threadIdx.x;
  float4 v = ((const float4*)c_sq)[t];
  float m = fmaxf(fmaxf(v.x, v.y), fmaxf(v.z, v.w));
#pragma unroll
  for (int off = 32; off > 0; off >>= 1) m = fmaxf(m, __shfl_down(m, off, 64));
  int lane = (int)threadIdx.x & 63, w = (int)threadIdx.x >> 6;
  if (lane == 0) red[w] = m;
  __syncthreads();
  if (threadIdx.x == 0) {
    m = fmaxf(fmaxf(red[0], red[1]), fmaxf(red[2], red[3]));
    atomicMax(&ctl[32], __float_as_uint(m));
  }
}

// ---------------- scan: 1-term f16 MFMA (centroids=M rows), min per (q,32c-group) ----
// Grid (32 qb, 8 kc). Block 512 thr / 8 waves; wave owns 64c x 128q per ct.
// Queries persistent in LDS [kt 8][quad 4][row 128][8 f16] (B-operand).
// Centroid A-frags from global (same addressing as round 11's B-loads).
// C layout: row(=centroid)=quad*4+rg, col(=query)=lane&15.
__global__ __launch_bounds__(512, 2) void scan_kernel(
    const _Float16* __restrict__ x0, const _Float16* __restrict__ c0,
    const float* __restrict__ c_sq, float* __restrict__ dm) {
  __shared__ __align__(16) _Float16 As0[32768];   // 64 KiB

  const int qb = blockIdx.x, kc = blockIdx.y;
  const int tid = (int)threadIdx.x;
  const int lane = tid & 63, w = tid >> 6;
  const int col = lane & 15, quad = lane >> 4;
  const int qrow0 = qb * QTILE;

#pragma unroll
  for (int i = 0; i < 8; ++i) {
    int u = i * 512 + tid;                 // 0..4095 (16B chunks)
    int kt = u >> 9, q = (u >> 7) & 3, r = u & 127;
    gl_lds16(x0 + (size_t)(qrow0 + r) * DDIM + kt * 32 + q * 8, As0 + (size_t)u * 8);
  }
  __syncthreads();   // only barrier

  for (int ct = 0; ct < STSZ / 512; ++ct) {
    const int cbase = kc * STSZ + ct * 512 + w * 64;   // wave-private 64-c slice
    f32x4 acc[4][8];                                    // [cm][qn]
#pragma unroll
    for (int cm = 0; cm < 4; ++cm)
#pragma unroll
      for (int qn = 0; qn < 8; ++qn) acc[cm][qn] = (f32x4)0.0f;

#pragma unroll 2
    for (int kt = 0; kt < 8; ++kt) {
      const int k0 = kt * 32;
      half8 cf[4];
#pragma unroll
      for (int cm = 0; cm < 4; ++cm)
        cf[cm] = *(const half8*)(c0 + (size_t)(cbase + cm * 16 + col) * DDIM + k0 + quad * 8);
#pragma unroll
      for (int qn = 0; qn < 8; ++qn) {
        half8 qf = *(const half8*)(As0 + (((kt * 4 + quad) * QTILE) + qn * 16 + col) * 8);
#pragma unroll
        for (int cm = 0; cm < 4; ++cm)
          acc[cm][qn] = __builtin_amdgcn_mfma_f32_16x16x32_f16(cf[cm], qf, acc[cm][qn], 0, 0, 0);
      }
    }

    // epilogue: d = cs - 2*dot; min over 32 centroids (2 cm-tiles: in-lane rg + quad xor)
    f32x4 csv[4];
#pragma unroll
    for (int cm = 0; cm < 4; ++cm)
      csv[cm] = *(const f32x4*)(c_sq + cbase + cm * 16 + quad * 4);
#pragma unroll
    for (int h = 0; h < 2; ++h) {
      const int grp = kc * 256 + ct * 16 + w * 2 + h;   // identical dm indexing to r11
      float* dmg = dm + (size_t)grp * 4096 + qrow0;
#pragma unroll
      for (int qn = 0; qn < 8; ++qn) {
        float mq = INFINITY;
#pragma unroll
        for (int c2 = 0; c2 < 2; ++c2) {
          int cm = h * 2 + c2;
#pragma unroll
          for (int rg = 0; rg < 4; ++rg)
            mq = fminf(mq, fmaf(-2.0f, acc[cm][qn][rg], csv[cm][rg]));
        }
        mq = fminf(mq, __shfl_xor(mq, 16, 64));
        mq = fminf(mq, __shfl_xor(mq, 32, 64));
        if (quad == 0) dmg[qn * 16 + col] = mq;         // 16 lanes, 64 B dense
      }
    }
  }
}

// ---------------- pmin: partial column-min of dm ----------------
__global__ __launch_bounds__(256) void pmin_kernel(const float* __restrict__ dm,
                                                   float* __restrict__ pm) {
  int qc = blockIdx.x & 15, gc = blockIdx.x >> 4;
  int q = qc * 256 + (int)threadIdx.x;
  float m = INFINITY;
  for (int g = gc * 128; g < gc * 128 + 128; ++g)
    m = fminf(m, dm[(size_t)g * 4096 + q]);
  pm[gc * 4096 + q] = m;
}

// ---------------- tq: per-query threshold + pk init ----------------
__global__ __launch_bounds__(256) void tq_kernel(const float* __restrict__ pm,
                                                 const float* __restrict__ x,
                                                 const unsigned* __restrict__ ctl,
                                                 float* __restrict__ T,
                                                 unsigned long long* __restrict__ pk) {
  int q = blockIdx.x * 256 + (int)threadIdx.x;
  float M = INFINITY;
#pragma unroll
  for (int i = 0; i < 16; ++i) M = fminf(M, pm[i * 4096 + q]);
  float xsq = 0.f;
  const float4* xr = (const float4*)(x + (size_t)q * DDIM);
#pragma unroll 8
  for (int i = 0; i < 64; ++i) {
    float4 v = xr[i];
    xsq = fmaf(v.x, v.x, fmaf(v.y, v.y, fmaf(v.z, v.z, fmaf(v.w, v.w, xsq))));
  }
  float cmaxsq = __uint_as_float(ctl[32]);
  // rigorous 1-term f16 bound ~2^-9 ||x|| ||c||max; margin = 4x bound + 1.0 slack
  T[q] = M + 0.0078125f * sqrtf(xsq * cmaxsq) + 1.0f;
  pk[q] = 0xFFFFFFFFFFFFFFFFull;
}

// ---------------- emit: (q, group) pairs under threshold ----------------
__global__ __launch_bounds__(256) void emit_kernel(const float* __restrict__ dm,
                                                   const float* __restrict__ T,
                                                   unsigned* __restrict__ ctl,
                                                   unsigned* __restrict__ pairs) {
  int qc = blockIdx.x & 15, gc = blockIdx.x >> 4;
  int q = qc * 256 + (int)threadIdx.x;
  float t = T[q];
  for (int g = gc * 128; g < gc * 128 + 128; ++g)
    if (dm[(size_t)g * 4096 + q] <= t) {
      unsigned pos = atomicAdd(&ctl[0], 1u);
      if (pos < CAP) pairs[pos] = ((unsigned)g << 12) | (unsigned)q;
    }
}

// ---------------- rescore: exact f32 over each selected 32-c group ----------------
__global__ __launch_bounds__(256) void rescore_kernel(
    const unsigned* __restrict__ pairs, const unsigned* __restrict__ ctl,
    const float* __restrict__ x, const float* __restrict__ cent,
    const float* __restrict__ c_sq, unsigned long long* __restrict__ pk) {
  int W = blockIdx.x * 4 + ((int)threadIdx.x >> 6);
  int lane = (int)threadIdx.x & 63;
  int cnt = (int)ctl[0];
  if (cnt > CAP) cnt = CAP;
  for (int p = W; p < cnt; p += 4096) {
    unsigned pr = pairs[p];
    int q = (int)(pr & 4095u), grp = (int)(pr >> 12);
    int c = grp * 32 + (lane >> 1);
    int dh = (lane & 1) * 128;
    const float4* xr = (const float4*)(x + (size_t)q * DDIM + dh);
    const float4* cr = (const float4*)(cent + (size_t)c * DDIM + dh);
    float s = 0.f;
#pragma unroll
    for (int i = 0; i < 32; ++i) {
      float4 a = xr[i], bb = cr[i];
      s = fmaf(a.x, bb.x, fmaf(a.y, bb.y, fmaf(a.z, bb.z, fmaf(a.w, bb.w, s))));
    }
    s += __shfl_xor(s, 1, 64);
    float d = (lane & 1) ? INFINITY : fmaf(-2.0f, s, c_sq[c]);
    unsigned long long pkv = ((unsigned long long)fkey(d) << 32) | (unsigned)c;
#pragma unroll
    for (int off = 1; off < 64; off <<= 1) {
      unsigned long long o = __shfl_xor(pkv, off, 64);
      if (o < pkv) pkv = o;
    }
    if (lane == 0) atomicMin(&pk[q], pkv);
  }
}

// ---------------- final: gather winner (+ exact fallback, also on overflow) ----------
__global__ __launch_bounds__(256) void final_kernel(const unsigned long long* __restrict__ pk,
                                                    const unsigned* __restrict__ ctl,
                                                    const float* __restrict__ x,
                                                    const float* __restrict__ cent,
                                                    const float* __restrict__ c_sq,
                                                    float* __restrict__ out) {
  int q = blockIdx.x * 4 + ((int)threadIdx.x >> 6);
  int lane = (int)threadIdx.x & 63;
  unsigned long long e = pk[q];
  bool overflow = ctl[0] > CAP;
  int idx;
  if (e != 0xFFFFFFFFFFFFFFFFull && !overflow) {
    idx = (int)(unsigned)(e & 0xFFFFFFFFu);
  } else {
    const float4* xr = (const float4*)(x + (size_t)q * DDIM);
    unsigned long long best = 0xFFFFFFFFFFFFFFFFull;
    for (int c = lane; c < 65536; c += 64) {
      const float4* cr = (const float4*)(cent + (size_t)c * DDIM);
      float s = 0.f;
#pragma unroll 16
      for (int i = 0; i < 64; ++i) {
        float4 a = xr[i], bb = cr[i];
        s = fmaf(a.x, bb.x, fmaf(a.y, bb.y, fmaf(a.z, bb.z, fmaf(a.w, bb.w, s))));
      }
      float d = fmaf(-2.0f, s, c_sq[c]);
      unsigned long long pkv = ((unsigned long long)fkey(d) << 32) | (unsigned)c;
      if (pkv < best) best = pkv;
    }
#pragma unroll
    for (int off = 1; off < 64; off <<= 1) {
      unsigned long long o = __shfl_xor(best, off, 64);
      if (o < best) best = o;
    }
    idx = (int)(unsigned)(best & 0xFFFFFFFFu);
  }
  float4 v = ((const float4*)cent)[(size_t)idx * 64 + lane];
  ((float4*)out)[(size_t)q * 64 + lane] = v;
  if (lane == 0) out[(size_t)4096 * DDIM + q] = (float)idx;
}

extern "C" void kernel_launch(void* const* d_in, const int* in_sizes, int n_in,
                              void* d_out, int out_size, void* d_ws, size_t ws_size,
                              hipStream_t stream) {
  const float* x    = (const float*)d_in[1];   // [4096,256]
  const float* cent = (const float*)d_in[2];   // [65536,256]
  float* out = (float*)d_out;
  char* ws = (char*)d_ws;

  const size_t OFF_C0    = 0;           // 33,554,432  f16 hi(centroids)
  const size_t OFF_X0    = 33554432;    //  2,097,152  f16 hi(x)
  const size_t OFF_CSQ   = 35651584;    //    262,144
  const size_t OFF_CTL   = 35913728;    //        256
  const size_t OFF_DM    = 35913984;    // 33,554,432  f32[2048][4096]
  const size_t OFF_PM    = 69468416;    //    262,144  f32[16][4096]
  const size_t OFF_T     = 69730560;    //     16,384
  const size_t OFF_PK    = 69746944;    //     32,768  u64[4096]
  const size_t OFF_PAIRS = 69779712;    //  2,097,152  u32[524288]
  const size_t NEED      = 72089600;    // proven available since round 2
  if (ws_size < NEED) return;

  _Float16* c0 = (_Float16*)(ws + OFF_C0);
  _Float16* x0 = (_Float16*)(ws + OFF_X0);
  float* c_sq = (float*)(ws + OFF_CSQ);
  unsigned* ctl = (unsigned*)(ws + OFF_CTL);
  float* dm = (float*)(ws + OFF_DM);
  float* pm = (float*)(ws + OFF_PM);
  float* T  = (float*)(ws + OFF_T);
  unsigned long long* pk = (unsigned long long*)(ws + OFF_PK);
  unsigned* pairs = (unsigned*)(ws + OFF_PAIRS);

  initctl_kernel<<<1, 64, 0, stream>>>(ctl);
  splitc_kernel<<<16384, 256, 0, stream>>>(cent, c0, c_sq);
  splitx_kernel<<<1024, 256, 0, stream>>>(x, x0, 4096 * 256 / 4);
  cmax_kernel<<<64, 256, 0, stream>>>(c_sq, ctl);
  scan_kernel<<<dim3(32, 8), 512, 0, stream>>>(x0, c0, c_sq, dm);
  pmin_kernel<<<256, 256, 0, stream>>>(dm, pm);
  tq_kernel<<<16, 256, 0, stream>>>(pm, x, ctl, T, pk);
  emit_kernel<<<256, 256, 0, stream>>>(dm, T, ctl, pairs);
  rescore_kernel<<<1024, 256, 0, stream>>>(pairs, ctl, x, cent, c_sq, pk);
  final_kernel<<<1024, 256, 0, stream>>>(pk, ctl, x, cent, c_sq, out);
}